// Round 3
// baseline (296.877 us; speedup 1.0000x reference)
//
#include <hip/hip_runtime.h>
#include <math.h>

#define NN 10000
#define EE 160000
#define MP 10112   // 79*128, padded node count
#define EPSBN 1e-5f

typedef __attribute__((ext_vector_type(8))) short short8;
typedef __attribute__((ext_vector_type(4))) short short4v;
typedef __attribute__((ext_vector_type(4))) float f32x4;

__device__ __forceinline__ short f2bf(float f) {
    union { float f; unsigned u; } v; v.f = f;
    unsigned r = v.u + 0x7FFF + ((v.u >> 16) & 1);
    return (short)(r >> 16);
}
__device__ __forceinline__ float bf2f(unsigned short u) {
    union { unsigned u; float f; } v; v.u = ((unsigned)u) << 16;
    return v.f;
}
__device__ __forceinline__ void gload16(const short* g, short* l) {
    __builtin_amdgcn_global_load_lds((const __attribute__((address_space(1))) void*)g,
                                     (__attribute__((address_space(3))) void*)l, 16, 0, 0);
}

// ---------------- CSR build ----------------

__global__ void count_kernel(const int* __restrict__ dst, int* __restrict__ deg, int E) {
    int e = blockIdx.x * blockDim.x + threadIdx.x;
    if (e < E) atomicAdd(&deg[dst[e]], 1);
}

__global__ __launch_bounds__(1024) void scan_kernel(const int* __restrict__ deg, int* __restrict__ off,
                                                    int* __restrict__ cursor, int n) {
    __shared__ int sm[1024];
    const int C = 10;
    int t = threadIdx.x;
    int base = t * C;
    int loc[C];
    int acc = 0;
#pragma unroll
    for (int i = 0; i < C; i++) {
        int idx = base + i;
        int v = (idx < n) ? deg[idx] : 0;
        loc[i] = acc;
        acc += v;
    }
    sm[t] = acc;
    __syncthreads();
    for (int d = 1; d < 1024; d <<= 1) {
        int v = (t >= d) ? sm[t - d] : 0;
        __syncthreads();
        sm[t] += v;
        __syncthreads();
    }
    int prefix = (t > 0) ? sm[t - 1] : 0;
#pragma unroll
    for (int i = 0; i < C; i++) {
        int idx = base + i;
        if (idx < n) {
            int o = prefix + loc[i];
            off[idx] = o;
            cursor[idx] = o;
        }
    }
    if (t == 1023) off[n] = sm[1023];
}

__global__ void fill_kernel(const int* __restrict__ src, const int* __restrict__ dst,
                            const float* __restrict__ ew, int* __restrict__ cursor,
                            int* __restrict__ psrc, float* __restrict__ pew, int E) {
    int e = blockIdx.x * blockDim.x + threadIdx.x;
    if (e < E) {
        int d = dst[e];
        int slot = atomicAdd(&cursor[d], 1);
        psrc[slot] = src[e];
        pew[slot] = ew[e];
    }
}

// ---------------- weights convert (all 3 layers in one kernel) ----------------
// Bt[j][k]: j<fo -> wrel[k][j]; j>=fo -> wroot[k][j-fo]; zero-pad k>=K

__global__ void conv_w_all(const float* __restrict__ w1r, const float* __restrict__ w1o,
                           const float* __restrict__ w2r, const float* __restrict__ w2o,
                           const float* __restrict__ w3r, const float* __restrict__ w3o,
                           short* __restrict__ B1, short* __restrict__ B2, short* __restrict__ B3) {
    int j = blockIdx.x;
    const float *Wr, *Wo;
    short* Bt;
    int K, Kp, fo, row;
    if (j < 512)      { row = j;       Wr = w1r; Wo = w1o; Bt = B1; K = 517; Kp = 576; fo = 256; }
    else if (j < 768) { row = j - 512; Wr = w2r; Wo = w2o; Bt = B2; K = 256; Kp = 256; fo = 128; }
    else              { row = j - 768; Wr = w3r; Wo = w3o; Bt = B3; K = 128; Kp = 128; fo = 64; }
    const float* W = (row < fo) ? Wr : Wo;
    int col = (row < fo) ? row : row - fo;
    for (int k = threadIdx.x; k < Kp; k += 256) {
        short v = 0;
        if (k < K) v = f2bf(W[(size_t)k * fo + col]);
        Bt[(size_t)row * Kp + k] = v;
    }
}

// ---------------- MFMA GEMM with fused A-transform ----------------
// MODE 0: A = x f32 [NN,K], convert only (guarded: rows<NN, k<K)
// MODE 1: A = hio f32 [MP,K], apply BN(scale/shift from sums)+ReLU, convert
// Tile 128x128, BK=64. Writes Yrel bf16 [MP,fo] and Hroot f32 [MP,fo] (+brel).

template <int MODE>
__global__ __launch_bounds__(256) void mfma_gemm(const float* __restrict__ A,
                                                 const short* __restrict__ Bt,
                                                 short* __restrict__ Yrel,
                                                 float* __restrict__ Hroot,
                                                 const float* __restrict__ brel,
                                                 const float* __restrict__ ssum,
                                                 const float* __restrict__ ssumsq,
                                                 const float* __restrict__ bng,
                                                 const float* __restrict__ bnb,
                                                 int K, int Kp, int fo) {
    __shared__ short Als[128 * 64];
    __shared__ short Bls[128 * 64];
    __shared__ float scs[256], shs[256];

    int m0 = blockIdx.x * 128;
    int n0 = blockIdx.y * 128;
    int t = threadIdx.x;
    int lane = t & 63;
    int wid = t >> 6;

    if (MODE == 1) {
        for (int f = t; f < K; f += 256) {
            float mean = ssum[f] / (float)NN;
            float var = ssumsq[f] / (float)NN - mean * mean;
            var = fmaxf(var, 0.f);
            float sc = bng[f] * rsqrtf(var + EPSBN);
            scs[f] = sc;
            shs[f] = bnb[f] - mean * sc;
        }
        __syncthreads();
    }

    f32x4 acc[2][8];
#pragma unroll
    for (int i = 0; i < 2; i++)
#pragma unroll
        for (int j = 0; j < 8; j++) acc[i][j] = (f32x4){0.f, 0.f, 0.f, 0.f};

    for (int k0 = 0; k0 < Kp; k0 += 64) {
        // B tile: 128 (n) x 64 (k) bf16 via global_load_lds, pre-swizzled source
#pragma unroll
        for (int i = 0; i < 4; i++) {
            int idx = i * 256 + t;
            int row = idx >> 3;
            int pc = idx & 7;
            gload16(Bt + (size_t)(n0 + row) * Kp + k0 + ((pc ^ (row & 7)) << 3), &Bls[idx << 3]);
        }
        // A tile: 128 (m) x 64 (k) f32 reg-staged with transform -> bf16
#pragma unroll
        for (int i = 0; i < 8; i++) {
            int idx = i * 256 + t;
            int row = idx >> 4;
            int fc = idx & 15;
            int g = m0 + row;
            int kb = k0 + (fc << 2);
            float v[4];
            if (MODE == 0) {
                const float* ap = A + (size_t)g * K + kb;
                bool gr = (g < NN);
#pragma unroll
                for (int j = 0; j < 4; j++) v[j] = (gr && kb + j < K) ? ap[j] : 0.f;
            } else {
                f32x4 x4 = *(const f32x4*)(A + (size_t)g * K + kb);
#pragma unroll
                for (int j = 0; j < 4; j++) v[j] = fmaxf(0.f, x4[j] * scs[kb + j] + shs[kb + j]);
            }
            short4v s;
#pragma unroll
            for (int j = 0; j < 4; j++) s[j] = f2bf(v[j]);
            *(short4v*)&Als[row * 64 + (((fc >> 1) ^ (row & 7)) << 3) + ((fc & 1) << 2)] = s;
        }
        __syncthreads();
#pragma unroll
        for (int kk = 0; kk < 2; kk++) {
            short8 af[2], bfr[8];
#pragma unroll
            for (int mi = 0; mi < 2; mi++) {
                int row = wid * 32 + mi * 16 + (lane & 15);
                int cc = kk * 4 + (lane >> 4);
                af[mi] = *(const short8*)&Als[(row * 8 + (cc ^ (row & 7))) * 8];
            }
#pragma unroll
            for (int ni = 0; ni < 8; ni++) {
                int row = ni * 16 + (lane & 15);
                int cc = kk * 4 + (lane >> 4);
                bfr[ni] = *(const short8*)&Bls[(row * 8 + (cc ^ (row & 7))) * 8];
            }
#pragma unroll
            for (int mi = 0; mi < 2; mi++)
#pragma unroll
                for (int ni = 0; ni < 8; ni++)
                    acc[mi][ni] = __builtin_amdgcn_mfma_f32_16x16x32_bf16(af[mi], bfr[ni], acc[mi][ni], 0, 0, 0);
        }
        __syncthreads();
    }

#pragma unroll
    for (int mi = 0; mi < 2; mi++) {
#pragma unroll
        for (int ni = 0; ni < 8; ni++) {
            int gn = n0 + ni * 16 + (lane & 15);
            int row0 = m0 + wid * 32 + mi * 16 + (lane >> 4) * 4;
            f32x4 v = acc[mi][ni];
            if (gn < fo) {
#pragma unroll
                for (int r = 0; r < 4; r++) Yrel[(size_t)(row0 + r) * fo + gn] = f2bf(v[r]);
            } else {
                float bb = brel[gn - fo];
#pragma unroll
                for (int r = 0; r < 4; r++) Hroot[(size_t)(row0 + r) * fo + (gn - fo)] = v[r] + bb;
            }
        }
    }
}

// ---------------- aggregation + BN stats ----------------
// hio[n,f] += sum_e w*Yrel[src,f]  (hio preloaded with root+bias by gemm epilogue)
// accumulates per-thread sum/sumsq over ITERS nodes, LDS-reduce, global atomic.

template <int FO, int NPB, int ITERS>
__global__ __launch_bounds__(256) void agg_stats(const short* __restrict__ Yrel,
                                                 float* __restrict__ hio,
                                                 const int* __restrict__ off,
                                                 const int* __restrict__ psrc,
                                                 const float* __restrict__ pew,
                                                 float* __restrict__ ssum,
                                                 float* __restrict__ ssumsq) {
    const int G = FO / 2;
    __shared__ float sm[2 * FO];
    int t = threadIdx.x;
    int g = t / G;
    int tf = t % G;
    int f = tf * 2;
    float s0 = 0.f, s1 = 0.f, q0 = 0.f, q1 = 0.f;
#pragma unroll
    for (int it = 0; it < ITERS; it++) {
        int n = blockIdx.x * (NPB * ITERS) + it * NPB + g;
        if (n < NN) {
            float a0 = 0.f, a1 = 0.f;
            int e0 = off[n], e1 = off[n + 1];
            size_t o = (size_t)n * FO + f;
            float h0 = hio[o], h1 = hio[o + 1];
            for (int e = e0; e < e1; e++) {
                int s = psrc[e];
                float w = pew[e];
                unsigned pk = *(const unsigned*)(Yrel + (size_t)s * FO + f);
                a0 += w * bf2f((unsigned short)(pk & 0xffff));
                a1 += w * bf2f((unsigned short)(pk >> 16));
            }
            float v0 = h0 + a0, v1 = h1 + a1;
            hio[o] = v0;
            hio[o + 1] = v1;
            s0 += v0; q0 += v0 * v0;
            s1 += v1; q1 += v1 * v1;
        }
    }
    if (t < FO) { sm[t] = 0.f; sm[FO + t] = 0.f; }
    __syncthreads();
    atomicAdd(&sm[f], s0);
    atomicAdd(&sm[f + 1], s1);
    atomicAdd(&sm[FO + f], q0);
    atomicAdd(&sm[FO + f + 1], q1);
    __syncthreads();
    if (t < FO) {
        atomicAdd(&ssum[t], sm[t]);
        atomicAdd(&ssumsq[t], sm[FO + t]);
    }
}

// ---------------- head: BN3 + ReLU + dot(wlin) + log_sigmoid ----------------

__global__ void head_kernel(const float* __restrict__ hio,
                            const float* __restrict__ ssum, const float* __restrict__ ssumsq,
                            const float* __restrict__ g3, const float* __restrict__ b3,
                            const float* __restrict__ wlin, const float* __restrict__ blin,
                            float* __restrict__ tmp) {
    int lane = threadIdx.x & 63;
    int wv = threadIdx.x >> 6;
    int n = blockIdx.x * 4 + wv;
    float mean = ssum[lane] / (float)NN;
    float var = ssumsq[lane] / (float)NN - mean * mean;
    var = fmaxf(var, 0.f);
    float sc = g3[lane] * rsqrtf(var + EPSBN);
    float sh = b3[lane] - mean * sc;
    float v = fmaxf(0.f, hio[(size_t)n * 64 + lane] * sc + sh);
    float p = v * wlin[lane];
#pragma unroll
    for (int o = 32; o > 0; o >>= 1) p += __shfl_down(p, o, 64);
    if (lane == 0) {
        float x = p + blin[0];
        float ls = (x >= 0.f) ? (-log1pf(expf(-x))) : (x - log1pf(expf(x)));
        tmp[n] = ls;
    }
}

// ---------------- logsumexp + final subtract (one block) ----------------

__global__ __launch_bounds__(1024) void lse_final(const float* __restrict__ tmp, float* __restrict__ out) {
    __shared__ float sm[1024];
    int t = threadIdx.x;
    float m = -INFINITY;
    for (int i = t; i < NN; i += 1024) m = fmaxf(m, tmp[i]);
    sm[t] = m;
    __syncthreads();
    for (int s = 512; s > 0; s >>= 1) {
        if (t < s) sm[t] = fmaxf(sm[t], sm[t + s]);
        __syncthreads();
    }
    float M = sm[0];
    __syncthreads();
    float acc = 0.f;
    for (int i = t; i < NN; i += 1024) acc += expf(tmp[i] - M);
    sm[t] = acc;
    __syncthreads();
    for (int s = 512; s > 0; s >>= 1) {
        if (t < s) sm[t] += sm[t + s];
        __syncthreads();
    }
    float L = M + logf(sm[0]);
    for (int i = t; i < NN; i += 1024) out[i] = tmp[i] - L;
}

// ---------------- launch ----------------

extern "C" void kernel_launch(void* const* d_in, const int* in_sizes, int n_in,
                              void* d_out, int out_size, void* d_ws, size_t ws_size,
                              hipStream_t stream) {
    const float* x  = (const float*)d_in[0];
    const int* ei   = (const int*)d_in[1];
    const float* ew = (const float*)d_in[2];
    const int* src = ei;
    const int* dst = ei + EE;

    const float* wrel[3]  = { (const float*)d_in[3],  (const float*)d_in[8],  (const float*)d_in[13] };
    const float* brel[3]  = { (const float*)d_in[4],  (const float*)d_in[9],  (const float*)d_in[14] };
    const float* wroot[3] = { (const float*)d_in[5],  (const float*)d_in[10], (const float*)d_in[15] };
    const float* bng[3]   = { (const float*)d_in[6],  (const float*)d_in[11], (const float*)d_in[16] };
    const float* bnb[3]   = { (const float*)d_in[7],  (const float*)d_in[12], (const float*)d_in[17] };
    const float* wlin = (const float*)d_in[18];
    const float* blin = (const float*)d_in[19];
    float* out = (float*)d_out;

    char* p = (char*)d_ws;
    auto alloc = [&](size_t bytes) { char* r = p; p += (bytes + 255) & ~(size_t)255; return r; };

    int*   deg     = (int*)alloc(NN * 4);           // memset region start
    float* ssumAll = (float*)alloc(1536 * 4);       // 3 layers x (sum[256]+sumsq[256])
    int*   off     = (int*)alloc((NN + 4) * 4);
    int*   cursor  = (int*)alloc(NN * 4);
    int*   psrc    = (int*)alloc(EE * 4);
    float* pew     = (float*)alloc(EE * 4);
    short* B1t     = (short*)alloc((size_t)512 * 576 * 2);
    short* B2t     = (short*)alloc((size_t)256 * 256 * 2);
    short* B3t     = (short*)alloc((size_t)128 * 128 * 2);
    short* Yrel    = (short*)alloc((size_t)MP * 256 * 2);
    float* hA      = (float*)alloc((size_t)MP * 256 * 4);
    float* hB      = (float*)alloc((size_t)MP * 128 * 4);
    float* hC      = (float*)alloc((size_t)MP * 64 * 4);
    float* tmp     = (float*)alloc(NN * 4);

    float* ss[3]  = { ssumAll,       ssumAll + 512,  ssumAll + 1024 };
    float* sq[3]  = { ssumAll + 256, ssumAll + 768,  ssumAll + 1280 };

    // one memset covers deg (+pad) + all BN sums (contiguous allocs)
    hipMemsetAsync(deg, 0, (size_t)((char*)(ssumAll + 1536) - (char*)deg), stream);

    count_kernel<<<(EE + 255) / 256, 256, 0, stream>>>(dst, deg, EE);
    scan_kernel<<<1, 1024, 0, stream>>>(deg, off, cursor, NN);
    fill_kernel<<<(EE + 255) / 256, 256, 0, stream>>>(src, dst, ew, cursor, psrc, pew, EE);
    conv_w_all<<<896, 256, 0, stream>>>(wrel[0], wroot[0], wrel[1], wroot[1], wrel[2], wroot[2],
                                        B1t, B2t, B3t);

    // layer 1
    mfma_gemm<0><<<dim3(MP / 128, 4), 256, 0, stream>>>(x, B1t, Yrel, hA, brel[0],
                                                        nullptr, nullptr, nullptr, nullptr, 517, 576, 256);
    agg_stats<256, 2, 10><<<500, 256, 0, stream>>>(Yrel, hA, off, psrc, pew, ss[0], sq[0]);
    // layer 2
    mfma_gemm<1><<<dim3(MP / 128, 2), 256, 0, stream>>>(hA, B2t, Yrel, hB, brel[1],
                                                        ss[0], sq[0], bng[0], bnb[0], 256, 256, 128);
    agg_stats<128, 4, 5><<<500, 256, 0, stream>>>(Yrel, hB, off, psrc, pew, ss[1], sq[1]);
    // layer 3
    mfma_gemm<1><<<dim3(MP / 128, 1), 256, 0, stream>>>(hB, B3t, Yrel, hC, brel[2],
                                                        ss[1], sq[1], bng[1], bnb[1], 128, 128, 64);
    agg_stats<64, 8, 2><<<625, 256, 0, stream>>>(Yrel, hC, off, psrc, pew, ss[2], sq[2]);

    head_kernel<<<2500, 256, 0, stream>>>(hC, ss[2], sq[2], bng[2], bnb[2], wlin, blin, tmp);
    lse_final<<<1, 1024, 0, stream>>>(tmp, out);
}